// Round 7
// baseline (144.656 us; speedup 1.0000x reference)
//
#include <hip/hip_runtime.h>
#include <stdint.h>

#define EPS_BN 1e-5f

#define C 256
#define H 28
#define W 28
#define R196 196
#define M_TOT 12544
#define K1 2304

typedef __attribute__((ext_vector_type(8))) short bf16x8;
typedef __attribute__((ext_vector_type(4))) float f32x4;
typedef __attribute__((ext_vector_type(4))) unsigned short u16x4;
typedef unsigned short ushort_t;

__device__ __forceinline__ unsigned short sgn_bf16(float v) {
    return v > 0.f ? (unsigned short)0x3F80
                   : (v < 0.f ? (unsigned short)0xBF80 : (unsigned short)0);
}

__device__ __forceinline__ void gload16(const void* g, void* l) {
    __builtin_amdgcn_global_load_lds(
        (const __attribute__((address_space(1))) void*)g,
        (__attribute__((address_space(3))) void*)l, 16, 0, 0);
}

// ---------------------------------------------------------------------------
// Kernel 1: merged weight-prep (blocks 0..767) + sign/pool (blocks 768..1663).
// ---------------------------------------------------------------------------
__global__ __launch_bounds__(256) void prep_sign(
    const float* __restrict__ w1,
    const float* __restrict__ bn1_g, const float* __restrict__ bn1_b,
    const float* __restrict__ bn1_m, const float* __restrict__ bn1_v,
    const float* __restrict__ w21,
    const float* __restrict__ bn21_g, const float* __restrict__ bn21_b,
    const float* __restrict__ bn21_m, const float* __restrict__ bn21_v,
    const float* __restrict__ w22,
    const float* __restrict__ bn22_g, const float* __restrict__ bn22_b,
    const float* __restrict__ bn22_m, const float* __restrict__ bn22_v,
    const float* __restrict__ x, const float* __restrict__ bias,
    unsigned short* __restrict__ bw1, unsigned short* __restrict__ bw2,
    float* __restrict__ alpha1, float* __restrict__ beta1,
    float* __restrict__ alpha2, float* __restrict__ beta2,
    ushort_t* __restrict__ a1p, float* __restrict__ pool)
{
    __shared__ float lx[2][256][29];          // sign part; prep aliases lx[0]
    float* red = &lx[0][0][0];
    const int bid = blockIdx.x;
    const int t = threadIdx.x;

    if (bid < 768) {
        if (bid < 256) {
            const int oc = bid;
            const float* w = w1 + oc * K1;
            float s = 0.f;
            for (int i = t; i < K1; i += 256) s += fabsf(w[i]);
            red[t] = s; __syncthreads();
            for (int o = 128; o > 0; o >>= 1) {
                if (t < o) red[t] += red[t + o];
                __syncthreads();
            }
            const float scale = red[0] * (1.f / (float)K1);
            if (t == 0) {
                const float inv = bn1_g[oc] * rsqrtf(bn1_v[oc] + EPS_BN);
                alpha1[oc] = scale * inv;
                beta1[oc]  = bn1_b[oc] - bn1_m[oc] * inv;
            }
            // write-coalesced: o = tap*256+ic; reads hit L1 (row = 9.2KB)
            for (int o = t; o < K1; o += 256) {
                const int tap = o >> 8, ic = o & 255;
                bw1[oc * K1 + tap * 256 + ic] = sgn_bf16(w[ic * 9 + tap]);
            }
        } else {
            const bool br2 = (bid >= 512);
            const int oc = (bid - 256) & 255;
            const float* w = (br2 ? w22 : w21) + oc * 256;
            red[t] = fabsf(w[t]); __syncthreads();
            for (int o = 128; o > 0; o >>= 1) {
                if (t < o) red[t] += red[t + o];
                __syncthreads();
            }
            const float scale = red[0] * (1.f / 256.f);
            const int n = oc + (br2 ? 256 : 0);
            if (t == 0) {
                const float g = br2 ? bn22_g[oc] : bn21_g[oc];
                const float b = br2 ? bn22_b[oc] : bn21_b[oc];
                const float m = br2 ? bn22_m[oc] : bn21_m[oc];
                const float v = br2 ? bn22_v[oc] : bn21_v[oc];
                const float inv = g * rsqrtf(v + EPS_BN);
                alpha2[n] = scale * inv;
                beta2[n]  = b - m * inv;
            }
            bw2[n * 256 + t] = sgn_bf16(w[t]);
        }
        return;
    }

    // ---- sign(x+bias) -> padded NHWC a1p, + 2x2 avgpool ----
    const int bo = bid - 768;               // b*14 + oh
    const int b = bo / 14, oh = bo % 14;
    const float* xb = x + (size_t)(b * 256) * 784 + (2 * oh) * 28;

    for (int idx = t; idx < 2 * 28 * 256; idx += 256) {
        const int row = idx / 7168;
        const int rem = idx - row * 7168;
        const int c = rem / 28, iw = rem % 28;
        lx[row][c][iw] = xb[c * 784 + row * 28 + iw];
    }
    __syncthreads();

#pragma unroll
    for (int row = 0; row < 2; ++row) {
        ushort_t* orow = a1p + (size_t)((b * 30 + 2 * oh + row + 1) * 30) * 256;
        for (int idx = t; idx < 28 * 256; idx += 256) {
            const int c = idx & 255, iw = idx >> 8;
            orow[(iw + 1) * 256 + c] = sgn_bf16(lx[row][c][iw] + bias[c]);
        }
        orow[t] = 0;
        orow[29 * 256 + t] = 0;
    }

    for (int idx = t; idx < 256 * 14; idx += 256) {
        const int c = idx / 14, ow = idx % 14;
        pool[(size_t)(b * 256 + c) * 196 + oh * 14 + ow] =
            0.25f * (lx[0][c][2 * ow] + lx[0][c][2 * ow + 1] +
                     lx[1][c][2 * ow] + lx[1][c][2 * ow + 1]);
    }

    if (oh == 0) {
        ushort_t* r0  = a1p + (size_t)(b * 900) * 256;
        ushort_t* r29 = a1p + (size_t)(b * 900 + 29 * 30) * 256;
        for (int idx = t; idx < 30 * 256; idx += 256) { r0[idx] = 0; r29[idx] = 0; }
    }
}

// ---------------------------------------------------------------------------
// Kernel 2: conv1 (3x3 s2) GEMM. BM=64 BN=64 BK=64, 784 blocks (196m x 4n),
// 8 waves (2m x 4n), wave tile 32x16. A via gload_lds (16KB dbuf, swizzled);
// B (weights) loaded per-step straight to registers (wave-private rows,
// L2-hot), depth-2 pipelined via named afA/afB. Counted vmcnt(5).
// ---------------------------------------------------------------------------
__global__ __launch_bounds__(512, 6) void conv1_lds(
    const ushort_t* __restrict__ a1p,   // [64][30][30][256]
    const ushort_t* __restrict__ bw1,   // [256][2304]
    const float* __restrict__ alpha1, const float* __restrict__ beta1,
    const float* __restrict__ p,
    const float* __restrict__ rsb,
    const float* __restrict__ prg, const float* __restrict__ prb,
    const float* __restrict__ prz,
    float* __restrict__ out2,
    ushort_t* __restrict__ a2)
{
    __shared__ ushort_t lA[2][64 * 64];

    const int bid = blockIdx.x;
    const int wgid = (bid & 7) * 98 + (bid >> 3);   // 784 = 8*98
    const int mtile = wgid >> 2;        // ntile fastest -> same XCD shares A
    const int ntile = wgid & 3;

    const int tid = threadIdx.x;
    const int wave = tid >> 6;          // 0..7
    const int lane = tid & 63;
    const int col = lane & 15;
    const int krow = lane >> 4;
    const int wr = wave >> 2;           // m half (32 rows)
    const int wc = wave & 3;            // n quarter (16 cols)
    const int l8 = lane >> 3;
    const int s8 = lane & 7;
    const int swz = ((s8 ^ l8) << 3);

    int pbA;
    {
        const int grow = wave * 8 + l8;
        const int m = mtile * 64 + grow;
        const int b = m / 196, r = m % 196;
        const int oh = r / 14, ow = r % 14;
        pbA = ((b * 30 + 2 * oh) * 30 + 2 * ow) * 256 + swz;
    }
    // B: wave-private rows, direct to regs
    const ushort_t* bptr = bw1 + (ntile * 64 + wc * 16 + col) * K1 + krow * 8;

    int rswz[2];
#pragma unroll
    for (int ks = 0; ks < 2; ++ks)
        rswz[ks] = ((ks * 4 + krow) ^ (col & 7)) << 4;

    f32x4 acc[2] = {};
    bf16x8 afA[2], afB[2];

    auto stageA = [&](int step, int buf) {
        const int tap = step >> 2;
        const int kc0 = (step & 3) << 6;
        const int kh = tap / 3, kw = tap - kh * 3;
        const int aoff = (kh * 30 + kw) * 256 + kc0;
        gload16(a1p + pbA + aoff, (char*)&lA[buf][0] + wave * 1024);
    };
    auto loadB = [&](int step, bf16x8* dst) {
        dst[0] = *(const bf16x8*)(bptr + step * 64);
        dst[1] = *(const bf16x8*)(bptr + step * 64 + 32);
    };

#define CONV1_COMPUTE(BUF, AF)                                                  \
    {                                                                           \
        _Pragma("unroll")                                                       \
        for (int ks = 0; ks < 2; ++ks) {                                        \
            bf16x8 bf0 = *(const bf16x8*)((const char*)&lA[BUF][0] +            \
                              (wr * 32 + col) * 128 + rswz[ks]);                \
            bf16x8 bf1 = *(const bf16x8*)((const char*)&lA[BUF][0] +            \
                              (wr * 32 + 16 + col) * 128 + rswz[ks]);           \
            acc[0] = __builtin_amdgcn_mfma_f32_16x16x32_bf16(AF[ks], bf0, acc[0], 0, 0, 0); \
            acc[1] = __builtin_amdgcn_mfma_f32_16x16x32_bf16(AF[ks], bf1, acc[1], 0, 0, 0); \
        }                                                                       \
    }

    stageA(0, 0);
    loadB(0, afA);

    for (int s2 = 0; s2 < 18; ++s2) {
        const int t0 = 2 * s2;
        // half A: compute step t0 from buf0 with afA; prefetch t0+1
        stageA(t0 + 1, 1);
        loadB(t0 + 1, afB);
        asm volatile("s_waitcnt vmcnt(5)" ::: "memory");  // own A(t0) landed
        __builtin_amdgcn_s_barrier();
        __builtin_amdgcn_sched_barrier(0);
        CONV1_COMPUTE(0, afA);
        __builtin_amdgcn_sched_barrier(0);
        __builtin_amdgcn_s_barrier();
        // half B: compute step t0+1 from buf1 with afB; prefetch t0+2
        if (t0 + 2 < 36) {
            stageA(t0 + 2, 0);
            loadB(t0 + 2, afA);
            asm volatile("s_waitcnt vmcnt(5)" ::: "memory");
        } else {
            asm volatile("s_waitcnt vmcnt(0)" ::: "memory");
        }
        __builtin_amdgcn_s_barrier();
        __builtin_amdgcn_sched_barrier(0);
        CONV1_COMPUTE(1, afB);
        __builtin_amdgcn_sched_barrier(0);
        __builtin_amdgcn_s_barrier();
    }
#undef CONV1_COMPUTE

#pragma unroll
    for (int im = 0; im < 2; ++im) {
        const int m = mtile * 64 + wr * 32 + im * 16 + col;
        const int b = m / 196, r = m % 196;
        const int n0 = ntile * 64 + wc * 16 + krow * 4;
        u16x4 spack;
#pragma unroll
        for (int j = 0; j < 4; ++j) {
            const int n = n0 + j;
            const int idx = (b * 256 + n) * 196 + r;
            float v = alpha1[n] * acc[im][j] + beta1[n] + p[idx];
            const float t = v - prg[n];
            const float o = (t > 0.f ? t : prb[n] * t) + prz[n];
            out2[idx] = o;
            spack[j] = sgn_bf16(o + rsb[n]);
        }
        *(u16x4*)(a2 + m * 256 + n0) = spack;
    }
}

// ---------------------------------------------------------------------------
// Kernel 3: both 1x1 convs. BM=64 BN=64 K=256 (4 steps), 1568 blocks
// (196m x 8n), 8 waves. Same A-LDS + B-regs depth-2 structure.
// ---------------------------------------------------------------------------
__global__ __launch_bounds__(512, 6) void conv1x1_lds(
    const ushort_t* __restrict__ a2,
    const ushort_t* __restrict__ bw2,
    const float* __restrict__ alpha2, const float* __restrict__ beta2,
    const float* __restrict__ out2,
    const float* __restrict__ prg, const float* __restrict__ prb,
    const float* __restrict__ prz,
    float* __restrict__ out)
{
    __shared__ ushort_t lA[2][64 * 64];

    const int bid = blockIdx.x;
    const int wgid = (bid & 7) * 196 + (bid >> 3);  // 1568 = 8*196
    const int mtile = wgid >> 3;
    const int ntile = wgid & 7;

    const int tid = threadIdx.x;
    const int wave = tid >> 6;
    const int lane = tid & 63;
    const int col = lane & 15;
    const int krow = lane >> 4;
    const int wr = wave >> 2;
    const int wc = wave & 3;
    const int l8 = lane >> 3;
    const int s8 = lane & 7;
    const int swz = ((s8 ^ l8) << 3);

    const int pbA = (mtile * 64 + wave * 8 + l8) * 256 + swz;
    const ushort_t* bptr = bw2 + (ntile * 64 + wc * 16 + col) * 256 + krow * 8;

    int rswz[2];
#pragma unroll
    for (int ks = 0; ks < 2; ++ks)
        rswz[ks] = ((ks * 4 + krow) ^ (col & 7)) << 4;

    f32x4 acc[2] = {};
    bf16x8 afA[2], afB[2];

    auto stageA = [&](int step, int buf) {
        gload16(a2 + pbA + step * 64, (char*)&lA[buf][0] + wave * 1024);
    };
    auto loadB = [&](int step, bf16x8* dst) {
        dst[0] = *(const bf16x8*)(bptr + step * 64);
        dst[1] = *(const bf16x8*)(bptr + step * 64 + 32);
    };

#define CONV2_COMPUTE(BUF, AF)                                                  \
    {                                                                           \
        _Pragma("unroll")                                                       \
        for (int ks = 0; ks < 2; ++ks) {                                        \
            bf16x8 bf0 = *(const bf16x8*)((const char*)&lA[BUF][0] +            \
                              (wr * 32 + col) * 128 + rswz[ks]);                \
            bf16x8 bf1 = *(const bf16x8*)((const char*)&lA[BUF][0] +            \
                              (wr * 32 + 16 + col) * 128 + rswz[ks]);           \
            acc[0] = __builtin_amdgcn_mfma_f32_16x16x32_bf16(AF[ks], bf0, acc[0], 0, 0, 0); \
            acc[1] = __builtin_amdgcn_mfma_f32_16x16x32_bf16(AF[ks], bf1, acc[1], 0, 0, 0); \
        }                                                                       \
    }

    stageA(0, 0);
    loadB(0, afA);

    for (int s2 = 0; s2 < 2; ++s2) {
        const int t0 = 2 * s2;
        stageA(t0 + 1, 1);
        loadB(t0 + 1, afB);
        asm volatile("s_waitcnt vmcnt(5)" ::: "memory");
        __builtin_amdgcn_s_barrier();
        __builtin_amdgcn_sched_barrier(0);
        CONV2_COMPUTE(0, afA);
        __builtin_amdgcn_sched_barrier(0);
        __builtin_amdgcn_s_barrier();
        if (t0 + 2 < 4) {
            stageA(t0 + 2, 0);
            loadB(t0 + 2, afA);
            asm volatile("s_waitcnt vmcnt(5)" ::: "memory");
        } else {
            asm volatile("s_waitcnt vmcnt(0)" ::: "memory");
        }
        __builtin_amdgcn_s_barrier();
        __builtin_amdgcn_sched_barrier(0);
        CONV2_COMPUTE(1, afB);
        __builtin_amdgcn_sched_barrier(0);
        __builtin_amdgcn_s_barrier();
    }
#undef CONV2_COMPUTE

#pragma unroll
    for (int im = 0; im < 2; ++im) {
        const int m = mtile * 64 + wr * 32 + im * 16 + col;
        const int b = m / 196, r = m % 196;
#pragma unroll
        for (int j = 0; j < 4; ++j) {
            const int n = ntile * 64 + wc * 16 + krow * 4 + j;   // [0,512)
            const int oc = n & 255;
            float v = alpha2[n] * acc[im][j] + beta2[n]
                    + out2[(b * 256 + oc) * 196 + r];
            const float t = v - prg[oc];
            out[(size_t)(b * 512 + n) * 196 + r] =
                (t > 0.f ? t : prb[oc] * t) + prz[oc];
        }
    }
}

// ---------------------------------------------------------------------------
extern "C" void kernel_launch(void* const* d_in, const int* in_sizes, int n_in,
                              void* d_out, int out_size, void* d_ws, size_t ws_size,
                              hipStream_t stream)
{
    (void)in_sizes; (void)n_in; (void)out_size; (void)ws_size;

    const float* x         = (const float*)d_in[0];
    const float* rsign_b   = (const float*)d_in[1];
    const float* w1        = (const float*)d_in[2];
    const float* bn1_g     = (const float*)d_in[3];
    const float* bn1_b     = (const float*)d_in[4];
    const float* bn1_m     = (const float*)d_in[5];
    const float* bn1_v     = (const float*)d_in[6];
    const float* w21       = (const float*)d_in[7];
    const float* bn21_g    = (const float*)d_in[8];
    const float* bn21_b    = (const float*)d_in[9];
    const float* bn21_m    = (const float*)d_in[10];
    const float* bn21_v    = (const float*)d_in[11];
    const float* w22       = (const float*)d_in[12];
    const float* bn22_g    = (const float*)d_in[13];
    const float* bn22_b    = (const float*)d_in[14];
    const float* bn22_m    = (const float*)d_in[15];
    const float* bn22_v    = (const float*)d_in[16];
    const float* pr_gamma  = (const float*)d_in[17];
    const float* pr_beta   = (const float*)d_in[18];
    const float* pr_zeta   = (const float*)d_in[19];

    char* ws = (char*)d_ws;
    size_t off = 0;
    ushort_t* a1p = (ushort_t*)(ws + off); off += (size_t)14745600 * 2;
    ushort_t* bw1 = (ushort_t*)(ws + off); off += (size_t)589824 * 2;
    ushort_t* bw2 = (ushort_t*)(ws + off); off += (size_t)131072 * 2;
    float* pool   = (float*)(ws + off);    off += (size_t)3211264 * 4;
    float* out2   = (float*)(ws + off);    off += (size_t)3211264 * 4;
    ushort_t* a2  = (ushort_t*)(ws + off); off += (size_t)3211264 * 2;
    float* alpha1 = (float*)(ws + off);    off += 1024;
    float* beta1  = (float*)(ws + off);    off += 1024;
    float* alpha2 = (float*)(ws + off);    off += 2048;
    float* beta2  = (float*)(ws + off);    off += 2048;

    prep_sign<<<1664, 256, 0, stream>>>(
        w1, bn1_g, bn1_b, bn1_m, bn1_v,
        w21, bn21_g, bn21_b, bn21_m, bn21_v,
        w22, bn22_g, bn22_b, bn22_m, bn22_v,
        x, rsign_b,
        bw1, bw2, alpha1, beta1, alpha2, beta2, a1p, pool);

    conv1_lds<<<784, 512, 0, stream>>>(
        a1p, bw1, alpha1, beta1, pool, rsign_b,
        pr_gamma, pr_beta, pr_zeta, out2, a2);

    conv1x1_lds<<<1568, 512, 0, stream>>>(
        a2, bw2, alpha2, beta2, out2,
        pr_gamma, pr_beta, pr_zeta, (float*)d_out);
}

// Round 8
// 106.327 us; speedup vs baseline: 1.3605x; 1.3605x over previous
//
#include <hip/hip_runtime.h>
#include <stdint.h>

#define EPS_BN 1e-5f

#define C 256
#define H 28
#define W 28
#define R196 196
#define M_TOT 12544
#define K1 2304

typedef __attribute__((ext_vector_type(8))) short bf16x8;
typedef __attribute__((ext_vector_type(4))) float f32x4;
typedef __attribute__((ext_vector_type(4))) unsigned short u16x4;
typedef unsigned short ushort_t;

__device__ __forceinline__ unsigned short sgn_bf16(float v) {
    return v > 0.f ? (unsigned short)0x3F80
                   : (v < 0.f ? (unsigned short)0xBF80 : (unsigned short)0);
}

__device__ __forceinline__ void gload16(const void* g, void* l) {
    __builtin_amdgcn_global_load_lds(
        (const __attribute__((address_space(1))) void*)g,
        (__attribute__((address_space(3))) void*)l, 16, 0, 0);
}

// ---------------------------------------------------------------------------
// Kernel 1: merged weight-prep (blocks 0..767) + sign/pool (blocks 768..1663).
// ---------------------------------------------------------------------------
__global__ __launch_bounds__(256) void prep_sign(
    const float* __restrict__ w1,
    const float* __restrict__ bn1_g, const float* __restrict__ bn1_b,
    const float* __restrict__ bn1_m, const float* __restrict__ bn1_v,
    const float* __restrict__ w21,
    const float* __restrict__ bn21_g, const float* __restrict__ bn21_b,
    const float* __restrict__ bn21_m, const float* __restrict__ bn21_v,
    const float* __restrict__ w22,
    const float* __restrict__ bn22_g, const float* __restrict__ bn22_b,
    const float* __restrict__ bn22_m, const float* __restrict__ bn22_v,
    const float* __restrict__ x, const float* __restrict__ bias,
    unsigned short* __restrict__ bw1, unsigned short* __restrict__ bw2,
    float* __restrict__ alpha1, float* __restrict__ beta1,
    float* __restrict__ alpha2, float* __restrict__ beta2,
    ushort_t* __restrict__ a1p, float* __restrict__ pool)
{
    __shared__ float lx[2][256][29];          // sign part; prep aliases lx[0]
    float* red = &lx[0][0][0];
    const int bid = blockIdx.x;
    const int t = threadIdx.x;

    if (bid < 768) {
        if (bid < 256) {
            const int oc = bid;
            const float* w = w1 + oc * K1;
            float s = 0.f;
            for (int i = t; i < K1; i += 256) s += fabsf(w[i]);
            red[t] = s; __syncthreads();
            for (int o = 128; o > 0; o >>= 1) {
                if (t < o) red[t] += red[t + o];
                __syncthreads();
            }
            const float scale = red[0] * (1.f / (float)K1);
            if (t == 0) {
                const float inv = bn1_g[oc] * rsqrtf(bn1_v[oc] + EPS_BN);
                alpha1[oc] = scale * inv;
                beta1[oc]  = bn1_b[oc] - bn1_m[oc] * inv;
            }
            // write-coalesced: o = tap*256+ic; reads hit L1/L2 (row = 9.2KB)
            for (int o = t; o < K1; o += 256) {
                const int tap = o >> 8, ic = o & 255;
                bw1[oc * K1 + tap * 256 + ic] = sgn_bf16(w[ic * 9 + tap]);
            }
        } else {
            const bool br2 = (bid >= 512);
            const int oc = (bid - 256) & 255;
            const float* w = (br2 ? w22 : w21) + oc * 256;
            red[t] = fabsf(w[t]); __syncthreads();
            for (int o = 128; o > 0; o >>= 1) {
                if (t < o) red[t] += red[t + o];
                __syncthreads();
            }
            const float scale = red[0] * (1.f / 256.f);
            const int n = oc + (br2 ? 256 : 0);
            if (t == 0) {
                const float g = br2 ? bn22_g[oc] : bn21_g[oc];
                const float b = br2 ? bn22_b[oc] : bn21_b[oc];
                const float m = br2 ? bn22_m[oc] : bn21_m[oc];
                const float v = br2 ? bn22_v[oc] : bn21_v[oc];
                const float inv = g * rsqrtf(v + EPS_BN);
                alpha2[n] = scale * inv;
                beta2[n]  = b - m * inv;
            }
            bw2[n * 256 + t] = sgn_bf16(w[t]);
        }
        return;
    }

    // ---- sign(x+bias) -> padded NHWC a1p, + 2x2 avgpool ----
    const int bo = bid - 768;               // b*14 + oh
    const int b = bo / 14, oh = bo % 14;
    const float* xb = x + (size_t)(b * 256) * 784 + (2 * oh) * 28;

    for (int idx = t; idx < 2 * 28 * 256; idx += 256) {
        const int row = idx / 7168;
        const int rem = idx - row * 7168;
        const int c = rem / 28, iw = rem % 28;
        lx[row][c][iw] = xb[c * 784 + row * 28 + iw];
    }
    __syncthreads();

#pragma unroll
    for (int row = 0; row < 2; ++row) {
        ushort_t* orow = a1p + (size_t)((b * 30 + 2 * oh + row + 1) * 30) * 256;
        for (int idx = t; idx < 28 * 256; idx += 256) {
            const int c = idx & 255, iw = idx >> 8;
            orow[(iw + 1) * 256 + c] = sgn_bf16(lx[row][c][iw] + bias[c]);
        }
        orow[t] = 0;
        orow[29 * 256 + t] = 0;
    }

    for (int idx = t; idx < 256 * 14; idx += 256) {
        const int c = idx / 14, ow = idx % 14;
        pool[(size_t)(b * 256 + c) * 196 + oh * 14 + ow] =
            0.25f * (lx[0][c][2 * ow] + lx[0][c][2 * ow + 1] +
                     lx[1][c][2 * ow] + lx[1][c][2 * ow + 1]);
    }

    if (oh == 0) {
        ushort_t* r0  = a1p + (size_t)(b * 900) * 256;
        ushort_t* r29 = a1p + (size_t)(b * 900 + 29 * 30) * 256;
        for (int idx = t; idx < 30 * 256; idx += 256) { r0[idx] = 0; r29[idx] = 0; }
    }
}

// ---------------------------------------------------------------------------
// Kernel 2: conv1 (3x3 s2) GEMM. BM=64 BN=64 BK=64, 784 blocks (196m x 4n),
// 8 waves (2m x 4n), wave tile 32x16, 512 threads. DEPTH-3 counted-vmcnt
// pipeline (3 LDS buffers, 48KB; still 3 blocks/CU = grid limit): stage(t+2)
// issued at top of iter t, vmcnt(4) waits only tile-t's own 2 loads.
// ---------------------------------------------------------------------------
__global__ __launch_bounds__(512) void conv1_lds(
    const ushort_t* __restrict__ a1p,   // [64][30][30][256]
    const ushort_t* __restrict__ bw1,   // [256][2304]  (k = tap*256+ic)
    const float* __restrict__ alpha1, const float* __restrict__ beta1,
    const float* __restrict__ p,
    const float* __restrict__ rsb,
    const float* __restrict__ prg, const float* __restrict__ prb,
    const float* __restrict__ prz,
    float* __restrict__ out2,
    ushort_t* __restrict__ a2)
{
    __shared__ ushort_t lA[3][64 * 64];
    __shared__ ushort_t lB[3][64 * 64];

    const int bid = blockIdx.x;
    const int wgid = (bid & 7) * 98 + (bid >> 3);   // 784 = 8*98
    const int mtile = wgid >> 2;        // 0..195 (ntile fastest -> same XCD)
    const int ntile = wgid & 3;

    const int tid = threadIdx.x;
    const int wave = tid >> 6;          // 0..7
    const int lane = tid & 63;
    const int col = lane & 15;
    const int krow = lane >> 4;
    const int wr = wave >> 2;           // m half (32 rows)
    const int wc = wave & 3;            // n quarter (16 cols)
    const int l8 = lane >> 3;
    const int s8 = lane & 7;
    const int swz = ((s8 ^ l8) << 3);

    int pbA;
    {
        const int grow = wave * 8 + l8;
        const int m = mtile * 64 + grow;
        const int b = m / 196, r = m % 196;
        const int oh = r / 14, ow = r % 14;
        pbA = ((b * 30 + 2 * oh) * 30 + 2 * ow) * 256 + swz;
    }
    const int pbB = (ntile * 64 + wave * 8 + l8) * K1 + swz;

    int rswz[2];
#pragma unroll
    for (int ks = 0; ks < 2; ++ks)
        rswz[ks] = ((ks * 4 + krow) ^ (col & 7)) << 4;

    f32x4 acc[2] = {};

    auto stage = [&](int step, int buf) {
        const int tap = step >> 2;
        const int kc0 = (step & 3) << 6;
        const int kh = tap / 3, kw = tap - kh * 3;
        const int aoff = (kh * 30 + kw) * 256 + kc0;
        gload16(a1p + pbA + aoff, (char*)&lA[buf][0] + wave * 1024);
        gload16(bw1 + pbB + step * 64, (char*)&lB[buf][0] + wave * 1024);
    };

    stage(0, 0);
    stage(1, 1);

    int cur = 0;
    for (int step = 0; step < 36; ++step) {
        if (step + 2 < 36) {
            int nb = cur + 2; if (nb >= 3) nb -= 3;
            stage(step + 2, nb);                             // +2 loads in flight
            asm volatile("s_waitcnt vmcnt(4)" ::: "memory"); // tile-t's 2 done
        } else if (step + 1 < 36) {
            asm volatile("s_waitcnt vmcnt(2)" ::: "memory");
        } else {
            asm volatile("s_waitcnt vmcnt(0)" ::: "memory");
        }
        __builtin_amdgcn_s_barrier();        // all waves' tile-t loads landed
        __builtin_amdgcn_sched_barrier(0);

#pragma unroll
        for (int ks = 0; ks < 2; ++ks) {
            bf16x8 bf[2], af;
#pragma unroll
            for (int im = 0; im < 2; ++im) {
                const int row = wr * 32 + im * 16 + col;
                bf[im] = *(const bf16x8*)((const char*)&lA[cur][0] + row * 128 + rswz[ks]);
            }
            {
                const int row = wc * 16 + col;
                af = *(const bf16x8*)((const char*)&lB[cur][0] + row * 128 + rswz[ks]);
            }
#pragma unroll
            for (int im = 0; im < 2; ++im)
                acc[im] = __builtin_amdgcn_mfma_f32_16x16x32_bf16(
                    af, bf[im], acc[im], 0, 0, 0);
        }
        __builtin_amdgcn_sched_barrier(0);
        __builtin_amdgcn_s_barrier();        // cur fully read -> restageable
        if (++cur == 3) cur = 0;
    }

#pragma unroll
    for (int im = 0; im < 2; ++im) {
        const int m = mtile * 64 + wr * 32 + im * 16 + col;
        const int b = m / 196, r = m % 196;
        const int n0 = ntile * 64 + wc * 16 + krow * 4;
        u16x4 spack;
#pragma unroll
        for (int j = 0; j < 4; ++j) {
            const int n = n0 + j;
            const int idx = (b * 256 + n) * 196 + r;
            float v = alpha1[n] * acc[im][j] + beta1[n] + p[idx];
            const float t = v - prg[n];
            const float o = (t > 0.f ? t : prb[n] * t) + prz[n];
            out2[idx] = o;
            spack[j] = sgn_bf16(o + rsb[n]);
        }
        *(u16x4*)(a2 + m * 256 + n0) = spack;
    }
}

// ---------------------------------------------------------------------------
// Kernel 3: both 1x1 convs. BM=64 BN=64 K=256 (4 steps), 1568 blocks
// (196m x 8n), 8 waves, depth-2 (keeps 4 blocks/CU). R6 structure unchanged.
// ---------------------------------------------------------------------------
__global__ __launch_bounds__(512) void conv1x1_lds(
    const ushort_t* __restrict__ a2,
    const ushort_t* __restrict__ bw2,
    const float* __restrict__ alpha2, const float* __restrict__ beta2,
    const float* __restrict__ out2,
    const float* __restrict__ prg, const float* __restrict__ prb,
    const float* __restrict__ prz,
    float* __restrict__ out)
{
    __shared__ ushort_t lA[2][64 * 64];
    __shared__ ushort_t lB[2][64 * 64];

    const int bid = blockIdx.x;
    const int wgid = (bid & 7) * 196 + (bid >> 3);  // 1568 = 8*196
    const int mtile = wgid >> 3;
    const int ntile = wgid & 7;

    const int tid = threadIdx.x;
    const int wave = tid >> 6;
    const int lane = tid & 63;
    const int col = lane & 15;
    const int krow = lane >> 4;
    const int wr = wave >> 2;
    const int wc = wave & 3;
    const int l8 = lane >> 3;
    const int s8 = lane & 7;
    const int swz = ((s8 ^ l8) << 3);

    const int pbA = (mtile * 64 + wave * 8 + l8) * 256 + swz;
    const int pbB = (ntile * 64 + wave * 8 + l8) * 256 + swz;

    int rswz[2];
#pragma unroll
    for (int ks = 0; ks < 2; ++ks)
        rswz[ks] = ((ks * 4 + krow) ^ (col & 7)) << 4;

    f32x4 acc[2] = {};

    auto stage = [&](int step, int buf) {
        gload16(a2 + pbA + step * 64, (char*)&lA[buf][0] + wave * 1024);
        gload16(bw2 + pbB + step * 64, (char*)&lB[buf][0] + wave * 1024);
    };

    stage(0, 0);

    int cur = 0;
    for (int step = 0; step < 4; ++step) {
        if (step + 1 < 4) {
            stage(step + 1, cur ^ 1);
            asm volatile("s_waitcnt vmcnt(2)" ::: "memory");
        } else {
            asm volatile("s_waitcnt vmcnt(0)" ::: "memory");
        }
        __builtin_amdgcn_s_barrier();
        __builtin_amdgcn_sched_barrier(0);

#pragma unroll
        for (int ks = 0; ks < 2; ++ks) {
            bf16x8 bf[2], af;
#pragma unroll
            for (int im = 0; im < 2; ++im) {
                const int row = wr * 32 + im * 16 + col;
                bf[im] = *(const bf16x8*)((const char*)&lA[cur][0] + row * 128 + rswz[ks]);
            }
            {
                const int row = wc * 16 + col;
                af = *(const bf16x8*)((const char*)&lB[cur][0] + row * 128 + rswz[ks]);
            }
#pragma unroll
            for (int im = 0; im < 2; ++im)
                acc[im] = __builtin_amdgcn_mfma_f32_16x16x32_bf16(
                    af, bf[im], acc[im], 0, 0, 0);
        }
        __builtin_amdgcn_sched_barrier(0);
        __builtin_amdgcn_s_barrier();
        cur ^= 1;
    }

#pragma unroll
    for (int im = 0; im < 2; ++im) {
        const int m = mtile * 64 + wr * 32 + im * 16 + col;
        const int b = m / 196, r = m % 196;
#pragma unroll
        for (int j = 0; j < 4; ++j) {
            const int n = ntile * 64 + wc * 16 + krow * 4 + j;   // [0,512)
            const int oc = n & 255;
            float v = alpha2[n] * acc[im][j] + beta2[n]
                    + out2[(b * 256 + oc) * 196 + r];
            const float t = v - prg[oc];
            out[(size_t)(b * 512 + n) * 196 + r] =
                (t > 0.f ? t : prb[oc] * t) + prz[oc];
        }
    }
}

// ---------------------------------------------------------------------------
extern "C" void kernel_launch(void* const* d_in, const int* in_sizes, int n_in,
                              void* d_out, int out_size, void* d_ws, size_t ws_size,
                              hipStream_t stream)
{
    (void)in_sizes; (void)n_in; (void)out_size; (void)ws_size;

    const float* x         = (const float*)d_in[0];
    const float* rsign_b   = (const float*)d_in[1];
    const float* w1        = (const float*)d_in[2];
    const float* bn1_g     = (const float*)d_in[3];
    const float* bn1_b     = (const float*)d_in[4];
    const float* bn1_m     = (const float*)d_in[5];
    const float* bn1_v     = (const float*)d_in[6];
    const float* w21       = (const float*)d_in[7];
    const float* bn21_g    = (const float*)d_in[8];
    const float* bn21_b    = (const float*)d_in[9];
    const float* bn21_m    = (const float*)d_in[10];
    const float* bn21_v    = (const float*)d_in[11];
    const float* w22       = (const float*)d_in[12];
    const float* bn22_g    = (const float*)d_in[13];
    const float* bn22_b    = (const float*)d_in[14];
    const float* bn22_m    = (const float*)d_in[15];
    const float* bn22_v    = (const float*)d_in[16];
    const float* pr_gamma  = (const float*)d_in[17];
    const float* pr_beta   = (const float*)d_in[18];
    const float* pr_zeta   = (const float*)d_in[19];

    char* ws = (char*)d_ws;
    size_t off = 0;
    ushort_t* a1p = (ushort_t*)(ws + off); off += (size_t)14745600 * 2;
    ushort_t* bw1 = (ushort_t*)(ws + off); off += (size_t)589824 * 2;
    ushort_t* bw2 = (ushort_t*)(ws + off); off += (size_t)131072 * 2;
    float* pool   = (float*)(ws + off);    off += (size_t)3211264 * 4;
    float* out2   = (float*)(ws + off);    off += (size_t)3211264 * 4;
    ushort_t* a2  = (ushort_t*)(ws + off); off += (size_t)3211264 * 2;
    float* alpha1 = (float*)(ws + off);    off += 1024;
    float* beta1  = (float*)(ws + off);    off += 1024;
    float* alpha2 = (float*)(ws + off);    off += 2048;
    float* beta2  = (float*)(ws + off);    off += 2048;

    prep_sign<<<1664, 256, 0, stream>>>(
        w1, bn1_g, bn1_b, bn1_m, bn1_v,
        w21, bn21_g, bn21_b, bn21_m, bn21_v,
        w22, bn22_g, bn22_b, bn22_m, bn22_v,
        x, rsign_b,
        bw1, bw2, alpha1, beta1, alpha2, beta2, a1p, pool);

    conv1_lds<<<784, 512, 0, stream>>>(
        a1p, bw1, alpha1, beta1, pool, rsign_b,
        pr_gamma, pr_beta, pr_zeta, out2, a2);

    conv1x1_lds<<<1568, 512, 0, stream>>>(
        a2, bw2, alpha2, beta2, out2,
        pr_gamma, pr_beta, pr_zeta, (float*)d_out);
}

// Round 9
// 72.507 us; speedup vs baseline: 1.9951x; 1.4664x over previous
//
#include <hip/hip_runtime.h>
#include <stdint.h>

#define EPS_BN 1e-5f

#define C 256
#define H 28
#define W 28
#define R196 196
#define M_TOT 12544
#define K1 2304

typedef __attribute__((ext_vector_type(4))) int   i32x4;
typedef __attribute__((ext_vector_type(4))) float f32x4;
typedef unsigned short ushort_t;

__device__ __forceinline__ char sgn_i8(float v) {
    return v > 0.f ? (char)1 : (v < 0.f ? (char)-1 : (char)0);
}

__device__ __forceinline__ void gload16(const void* g, void* l) {
    __builtin_amdgcn_global_load_lds(
        (const __attribute__((address_space(1))) void*)g,
        (__attribute__((address_space(3))) void*)l, 16, 0, 0);
}

// ---------------------------------------------------------------------------
// Kernel 1: merged weight-prep (blocks 0..767) + sign/pool (blocks 768..1663).
// All sign tensors are int8 (+1/-1/0).
// ---------------------------------------------------------------------------
__global__ __launch_bounds__(256) void prep_sign(
    const float* __restrict__ w1,
    const float* __restrict__ bn1_g, const float* __restrict__ bn1_b,
    const float* __restrict__ bn1_m, const float* __restrict__ bn1_v,
    const float* __restrict__ w21,
    const float* __restrict__ bn21_g, const float* __restrict__ bn21_b,
    const float* __restrict__ bn21_m, const float* __restrict__ bn21_v,
    const float* __restrict__ w22,
    const float* __restrict__ bn22_g, const float* __restrict__ bn22_b,
    const float* __restrict__ bn22_m, const float* __restrict__ bn22_v,
    const float* __restrict__ x, const float* __restrict__ bias,
    char* __restrict__ bw1, char* __restrict__ bw2,
    float* __restrict__ alpha1, float* __restrict__ beta1,
    float* __restrict__ alpha2, float* __restrict__ beta2,
    char* __restrict__ a1p, float* __restrict__ pool)
{
    __shared__ float lx[2][256][29];          // sign part; prep aliases lx[0]
    float* red = &lx[0][0][0];
    const int bid = blockIdx.x;
    const int t = threadIdx.x;

    if (bid < 768) {
        if (bid < 256) {
            const int oc = bid;
            const float* w = w1 + oc * K1;
            float s = 0.f;
            for (int i = t; i < K1; i += 256) s += fabsf(w[i]);
            red[t] = s; __syncthreads();
            for (int o = 128; o > 0; o >>= 1) {
                if (t < o) red[t] += red[t + o];
                __syncthreads();
            }
            const float scale = red[0] * (1.f / (float)K1);
            if (t == 0) {
                const float inv = bn1_g[oc] * rsqrtf(bn1_v[oc] + EPS_BN);
                alpha1[oc] = scale * inv;
                beta1[oc]  = bn1_b[oc] - bn1_m[oc] * inv;
            }
            // k = tap*256 + ic (write-coalesced; reads hit L1/L2)
            for (int o = t; o < K1; o += 256) {
                const int tap = o >> 8, ic = o & 255;
                bw1[oc * K1 + tap * 256 + ic] = sgn_i8(w[ic * 9 + tap]);
            }
        } else {
            const bool br2 = (bid >= 512);
            const int oc = (bid - 256) & 255;
            const float* w = (br2 ? w22 : w21) + oc * 256;
            red[t] = fabsf(w[t]); __syncthreads();
            for (int o = 128; o > 0; o >>= 1) {
                if (t < o) red[t] += red[t + o];
                __syncthreads();
            }
            const float scale = red[0] * (1.f / 256.f);
            const int n = oc + (br2 ? 256 : 0);
            if (t == 0) {
                const float g = br2 ? bn22_g[oc] : bn21_g[oc];
                const float b = br2 ? bn22_b[oc] : bn21_b[oc];
                const float m = br2 ? bn22_m[oc] : bn21_m[oc];
                const float v = br2 ? bn22_v[oc] : bn21_v[oc];
                const float inv = g * rsqrtf(v + EPS_BN);
                alpha2[n] = scale * inv;
                beta2[n]  = b - m * inv;
            }
            bw2[n * 256 + t] = sgn_i8(w[t]);
        }
        return;
    }

    // ---- sign(x+bias) -> padded NHWC int8 a1p, + 2x2 avgpool ----
    const int bo = bid - 768;               // b*14 + oh
    const int b = bo / 14, oh = bo % 14;
    const float* xb = x + (size_t)(b * 256) * 784 + (2 * oh) * 28;

    for (int idx = t; idx < 2 * 28 * 256; idx += 256) {
        const int row = idx / 7168;
        const int rem = idx - row * 7168;
        const int c = rem / 28, iw = rem % 28;
        lx[row][c][iw] = xb[c * 784 + row * 28 + iw];
    }
    __syncthreads();

#pragma unroll
    for (int row = 0; row < 2; ++row) {
        char* orow = a1p + (size_t)((b * 30 + 2 * oh + row + 1) * 30) * 256;
        for (int idx = t; idx < 28 * 256; idx += 256) {
            const int c = idx & 255, iw = idx >> 8;
            orow[(iw + 1) * 256 + c] = sgn_i8(lx[row][c][iw] + bias[c]);
        }
        orow[t] = 0;
        orow[29 * 256 + t] = 0;
    }

    for (int idx = t; idx < 256 * 14; idx += 256) {
        const int c = idx / 14, ow = idx % 14;
        pool[(size_t)(b * 256 + c) * 196 + oh * 14 + ow] =
            0.25f * (lx[0][c][2 * ow] + lx[0][c][2 * ow + 1] +
                     lx[1][c][2 * ow] + lx[1][c][2 * ow + 1]);
    }

    if (oh == 0) {
        char* r0  = a1p + (size_t)(b * 900) * 256;
        char* r29 = a1p + (size_t)(b * 900 + 29 * 30) * 256;
        for (int idx = t; idx < 30 * 256; idx += 256) { r0[idx] = 0; r29[idx] = 0; }
    }
}

// ---------------------------------------------------------------------------
// Kernel 2: conv1 (3x3 s2) as i8 GEMM. M=12544 N=256 K=2304, BM=64 BN=64
// BK=128 (18 steps), 784 blocks (196m x 4n), 8 waves (2m x 4n), wave tile
// 32x16. mfma_i32_16x16x64_i8; depth-2 counted-vmcnt; 32KB LDS (4 blk/CU).
// LDS rows = 128B (128 i8), XOR swizzle (slot ^ row&7) both sides.
// ---------------------------------------------------------------------------
__global__ __launch_bounds__(512) void conv1_i8(
    const char* __restrict__ a1p,       // [64][30][30][256] i8
    const char* __restrict__ bw1,       // [256][2304] i8 (k = tap*256+ic)
    const float* __restrict__ alpha1, const float* __restrict__ beta1,
    const float* __restrict__ p,
    const float* __restrict__ rsb,
    const float* __restrict__ prg, const float* __restrict__ prb,
    const float* __restrict__ prz,
    float* __restrict__ out2,
    char* __restrict__ a2)              // [m][256] i8
{
    __shared__ char lA[2][64 * 128];
    __shared__ char lB[2][64 * 128];

    const int bid = blockIdx.x;
    const int wgid = (bid & 7) * 98 + (bid >> 3);   // 784 = 8*98
    const int mtile = wgid >> 2;        // 0..195 (ntile fastest -> same XCD)
    const int ntile = wgid & 3;

    const int tid = threadIdx.x;
    const int wave = tid >> 6;          // 0..7
    const int lane = tid & 63;
    const int col = lane & 15;
    const int krow = lane >> 4;
    const int wr = wave >> 2;           // m half (32 rows)
    const int wc = wave & 3;            // n quarter (16 cols)
    const int l8 = lane >> 3;           // row-within-8
    const int s8 = lane & 7;            // 16B slot
    const int swz = ((s8 ^ l8) << 4);   // pre-swizzled source byte offset

    int pbA;
    {
        const int grow = wave * 8 + l8;
        const int m = mtile * 64 + grow;
        const int b = m / 196, r = m % 196;
        const int oh = r / 14, ow = r % 14;
        pbA = ((b * 30 + 2 * oh) * 30 + 2 * ow) * 256 + swz;
    }
    const int pbB = (ntile * 64 + wave * 8 + l8) * K1 + swz;

    int rswz[2];
#pragma unroll
    for (int ks = 0; ks < 2; ++ks)
        rswz[ks] = ((ks * 4 + krow) ^ (col & 7)) << 4;

    i32x4 acc[2] = {};

    auto stage = [&](int step, int buf) {
        const int tap = step >> 1;              // 2 steps per tap (K=256/tap)
        const int kc0 = (step & 1) << 7;
        const int kh = tap / 3, kw = tap - kh * 3;
        const int aoff = (kh * 30 + kw) * 256 + kc0;
        gload16(a1p + pbA + aoff, &lA[buf][0] + wave * 1024);
        gload16(bw1 + pbB + step * 128, &lB[buf][0] + wave * 1024);
    };

    stage(0, 0);

    int cur = 0;
    for (int step = 0; step < 18; ++step) {
        if (step + 1 < 18) {
            stage(step + 1, cur ^ 1);                        // 2 new loads
            asm volatile("s_waitcnt vmcnt(2)" ::: "memory"); // tile-t's 2 done
        } else {
            asm volatile("s_waitcnt vmcnt(0)" ::: "memory");
        }
        __builtin_amdgcn_s_barrier();
        __builtin_amdgcn_sched_barrier(0);

#pragma unroll
        for (int ks = 0; ks < 2; ++ks) {        // each ks covers K=64
            i32x4 bf[2], af;
#pragma unroll
            for (int im = 0; im < 2; ++im) {
                const int row = wr * 32 + im * 16 + col;
                bf[im] = *(const i32x4*)(&lA[cur][0] + row * 128 + rswz[ks]);
            }
            {
                const int row = wc * 16 + col;
                af = *(const i32x4*)(&lB[cur][0] + row * 128 + rswz[ks]);
            }
#pragma unroll
            for (int im = 0; im < 2; ++im)
                acc[im] = __builtin_amdgcn_mfma_i32_16x16x64_i8(
                    af, bf[im], acc[im], 0, 0, 0);
        }
        __builtin_amdgcn_sched_barrier(0);
        __builtin_amdgcn_s_barrier();
        cur ^= 1;
    }

#pragma unroll
    for (int im = 0; im < 2; ++im) {
        const int m = mtile * 64 + wr * 32 + im * 16 + col;
        const int b = m / 196, r = m % 196;
        const int n0 = ntile * 64 + wc * 16 + krow * 4;
        char spack[4];
#pragma unroll
        for (int j = 0; j < 4; ++j) {
            const int n = n0 + j;
            const int idx = (b * 256 + n) * 196 + r;
            float v = alpha1[n] * (float)acc[im][j] + beta1[n] + p[idx];
            const float t = v - prg[n];
            const float o = (t > 0.f ? t : prb[n] * t) + prz[n];
            out2[idx] = o;
            spack[j] = sgn_i8(o + rsb[n]);
        }
        *(char4*)(a2 + m * 256 + n0) = *(char4*)spack;
    }
}

// ---------------------------------------------------------------------------
// Kernel 3: both 1x1 convs as single-shot i8 GEMM. M=12544 N=512 K=256
// (one staged tile, ONE barrier), 1568 blocks (196m x 8n), 8 waves.
// LDS tile = 2 k-halves x [64][128B] per operand (same swizzle as conv1).
// ---------------------------------------------------------------------------
__global__ __launch_bounds__(512) void conv1x1_i8(
    const char* __restrict__ a2,        // [m][256] i8
    const char* __restrict__ bw2,       // [512][256] i8
    const float* __restrict__ alpha2, const float* __restrict__ beta2,
    const float* __restrict__ out2,
    const float* __restrict__ prg, const float* __restrict__ prb,
    const float* __restrict__ prz,
    float* __restrict__ out)
{
    __shared__ char lA[2][64 * 128];    // [k-half][row][128B]
    __shared__ char lB[2][64 * 128];

    const int bid = blockIdx.x;
    const int wgid = (bid & 7) * 196 + (bid >> 3);  // 1568 = 8*196
    const int mtile = wgid >> 3;        // 0..195 (ntile fastest)
    const int ntile = wgid & 7;

    const int tid = threadIdx.x;
    const int wave = tid >> 6;
    const int lane = tid & 63;
    const int col = lane & 15;
    const int krow = lane >> 4;
    const int wr = wave >> 2;
    const int wc = wave & 3;
    const int l8 = lane >> 3;
    const int s8 = lane & 7;
    const int swz = ((s8 ^ l8) << 4);

    const int pbA = (mtile * 64 + wave * 8 + l8) * 256 + swz;
    const int pbB = (ntile * 64 + wave * 8 + l8) * 256 + swz;

    // stage everything once: 2 halves x (A,B)
#pragma unroll
    for (int h = 0; h < 2; ++h) {
        gload16(a2 + pbA + h * 128, &lA[h][0] + wave * 1024);
        gload16(bw2 + pbB + h * 128, &lB[h][0] + wave * 1024);
    }
    asm volatile("s_waitcnt vmcnt(0)" ::: "memory");
    __builtin_amdgcn_s_barrier();
    __builtin_amdgcn_sched_barrier(0);

    i32x4 acc[2] = {};
#pragma unroll
    for (int ks = 0; ks < 4; ++ks) {            // 4 x K=64
        const int h = ks >> 1, k2 = ks & 1;
        const int ro = ((k2 * 4 + krow) ^ (col & 7)) << 4;
        i32x4 bf[2], af;
#pragma unroll
        for (int im = 0; im < 2; ++im) {
            const int row = wr * 32 + im * 16 + col;
            bf[im] = *(const i32x4*)(&lA[h][0] + row * 128 + ro);
        }
        {
            const int row = wc * 16 + col;
            af = *(const i32x4*)(&lB[h][0] + row * 128 + ro);
        }
#pragma unroll
        for (int im = 0; im < 2; ++im)
            acc[im] = __builtin_amdgcn_mfma_i32_16x16x64_i8(
                af, bf[im], acc[im], 0, 0, 0);
    }

#pragma unroll
    for (int im = 0; im < 2; ++im) {
        const int m = mtile * 64 + wr * 32 + im * 16 + col;
        const int b = m / 196, r = m % 196;
#pragma unroll
        for (int j = 0; j < 4; ++j) {
            const int n = ntile * 64 + wc * 16 + krow * 4 + j;   // [0,512)
            const int oc = n & 255;
            float v = alpha2[n] * (float)acc[im][j] + beta2[n]
                    + out2[(b * 256 + oc) * 196 + r];
            const float t = v - prg[oc];
            out[(size_t)(b * 512 + n) * 196 + r] =
                (t > 0.f ? t : prb[oc] * t) + prz[oc];
        }
    }
}

// ---------------------------------------------------------------------------
extern "C" void kernel_launch(void* const* d_in, const int* in_sizes, int n_in,
                              void* d_out, int out_size, void* d_ws, size_t ws_size,
                              hipStream_t stream)
{
    (void)in_sizes; (void)n_in; (void)out_size; (void)ws_size;

    const float* x         = (const float*)d_in[0];
    const float* rsign_b   = (const float*)d_in[1];
    const float* w1        = (const float*)d_in[2];
    const float* bn1_g     = (const float*)d_in[3];
    const float* bn1_b     = (const float*)d_in[4];
    const float* bn1_m     = (const float*)d_in[5];
    const float* bn1_v     = (const float*)d_in[6];
    const float* w21       = (const float*)d_in[7];
    const float* bn21_g    = (const float*)d_in[8];
    const float* bn21_b    = (const float*)d_in[9];
    const float* bn21_m    = (const float*)d_in[10];
    const float* bn21_v    = (const float*)d_in[11];
    const float* w22       = (const float*)d_in[12];
    const float* bn22_g    = (const float*)d_in[13];
    const float* bn22_b    = (const float*)d_in[14];
    const float* bn22_m    = (const float*)d_in[15];
    const float* bn22_v    = (const float*)d_in[16];
    const float* pr_gamma  = (const float*)d_in[17];
    const float* pr_beta   = (const float*)d_in[18];
    const float* pr_zeta   = (const float*)d_in[19];

    char* ws = (char*)d_ws;
    size_t off = 0;
    char* a1p   = (char*)(ws + off);  off += (size_t)14745600;      // 14.7MB i8
    char* bw1   = (char*)(ws + off);  off += (size_t)589824;        // 0.6MB i8
    char* bw2   = (char*)(ws + off);  off += (size_t)131072;        // 0.13MB
    float* pool = (float*)(ws + off); off += (size_t)3211264 * 4;   // 12.8MB
    float* out2 = (float*)(ws + off); off += (size_t)3211264 * 4;   // 12.8MB
    char* a2    = (char*)(ws + off);  off += (size_t)3211264;       // 3.2MB i8
    float* alpha1 = (float*)(ws + off); off += 1024;
    float* beta1  = (float*)(ws + off); off += 1024;
    float* alpha2 = (float*)(ws + off); off += 2048;
    float* beta2  = (float*)(ws + off); off += 2048;

    prep_sign<<<1664, 256, 0, stream>>>(
        w1, bn1_g, bn1_b, bn1_m, bn1_v,
        w21, bn21_g, bn21_b, bn21_m, bn21_v,
        w22, bn22_g, bn22_b, bn22_m, bn22_v,
        x, rsign_b,
        bw1, bw2, alpha1, beta1, alpha2, beta2, a1p, pool);

    conv1_i8<<<784, 512, 0, stream>>>(
        a1p, bw1, alpha1, beta1, pool, rsign_b,
        pr_gamma, pr_beta, pr_zeta, out2, a2);

    conv1x1_i8<<<1568, 512, 0, stream>>>(
        a2, bw2, alpha2, beta2, out2,
        pr_gamma, pr_beta, pr_zeta, (float*)d_out);
}

// Round 10
// 61.722 us; speedup vs baseline: 2.3437x; 1.1747x over previous
//
#include <hip/hip_runtime.h>
#include <stdint.h>

#define EPS_BN 1e-5f

#define C 256
#define H 28
#define W 28
#define R196 196
#define M_TOT 12544
#define K1 2304

typedef __attribute__((ext_vector_type(4))) int   i32x4;
typedef __attribute__((ext_vector_type(4))) float f32x4;
typedef unsigned short ushort_t;
typedef unsigned int uint_t;

__device__ __forceinline__ char sgn_i8(float v) {
    return v > 0.f ? (char)1 : (v < 0.f ? (char)-1 : (char)0);
}
__device__ __forceinline__ uint_t sgn_b(float v) {   // sign as byte of u32
    return (uint_t)(unsigned char)sgn_i8(v);
}

__device__ __forceinline__ void gload16(const void* g, void* l) {
    __builtin_amdgcn_global_load_lds(
        (const __attribute__((address_space(1))) void*)g,
        (__attribute__((address_space(3))) void*)l, 16, 0, 0);
}

// channel-position permutation for conv1's K axis (a1p and bw1 share it):
//   p(ic) = ((ic & 63) << 2) | (ic >> 6);  ic(p) = ((p & 3) << 6) | (p >> 2)

// ---------------------------------------------------------------------------
// Kernel 1: blocks 0..767 weight prep; blocks 768..1663 sign(x+bias)->a1p
// (padded NHWC i8, permuted channel axis) + 2x2 avgpool.
// ---------------------------------------------------------------------------
__global__ __launch_bounds__(256) void prep_sign(
    const float* __restrict__ w1,
    const float* __restrict__ bn1_g, const float* __restrict__ bn1_b,
    const float* __restrict__ bn1_m, const float* __restrict__ bn1_v,
    const float* __restrict__ w21,
    const float* __restrict__ bn21_g, const float* __restrict__ bn21_b,
    const float* __restrict__ bn21_m, const float* __restrict__ bn21_v,
    const float* __restrict__ w22,
    const float* __restrict__ bn22_g, const float* __restrict__ bn22_b,
    const float* __restrict__ bn22_m, const float* __restrict__ bn22_v,
    const float* __restrict__ x, const float* __restrict__ bias,
    char* __restrict__ bw1, char* __restrict__ bw2,
    float* __restrict__ alpha1, float* __restrict__ beta1,
    float* __restrict__ alpha2, float* __restrict__ beta2,
    char* __restrict__ a1p, float* __restrict__ pool)
{
    __shared__ uint_t lsign[3584];            // [row][c][q] packed signs, 14KB
    float* red = (float*)lsign;
    const int bid = blockIdx.x;
    const int t = threadIdx.x;

    if (bid < 768) {
        if (bid < 256) {
            const int oc = bid;
            const float* w = w1 + oc * K1;
            float s = 0.f;
            for (int i = t; i < K1; i += 256) s += fabsf(w[i]);
            red[t] = s; __syncthreads();
            for (int o = 128; o > 0; o >>= 1) {
                if (t < o) red[t] += red[t + o];
                __syncthreads();
            }
            const float scale = red[0] * (1.f / (float)K1);
            if (t == 0) {
                const float inv = bn1_g[oc] * rsqrtf(bn1_v[oc] + EPS_BN);
                alpha1[oc] = scale * inv;
                beta1[oc]  = bn1_b[oc] - bn1_m[oc] * inv;
            }
            // K index = tap*256 + p ; ic = ((p&3)<<6)|(p>>2). p = t (fixed/lane).
            const int ic = ((t & 3) << 6) | (t >> 2);
#pragma unroll
            for (int tap = 0; tap < 9; ++tap)
                bw1[oc * K1 + tap * 256 + t] = sgn_i8(w[ic * 9 + tap]);
        } else {
            const bool br2 = (bid >= 512);
            const int oc = (bid - 256) & 255;
            const float* w = (br2 ? w22 : w21) + oc * 256;
            red[t] = fabsf(w[t]); __syncthreads();
            for (int o = 128; o > 0; o >>= 1) {
                if (t < o) red[t] += red[t + o];
                __syncthreads();
            }
            const float scale = red[0] * (1.f / 256.f);
            const int n = oc + (br2 ? 256 : 0);
            if (t == 0) {
                const float g = br2 ? bn22_g[oc] : bn21_g[oc];
                const float b = br2 ? bn22_b[oc] : bn21_b[oc];
                const float m = br2 ? bn22_m[oc] : bn21_m[oc];
                const float v = br2 ? bn22_v[oc] : bn21_v[oc];
                const float inv = g * rsqrtf(v + EPS_BN);
                alpha2[n] = scale * inv;
                beta2[n]  = b - m * inv;
            }
            bw2[n * 256 + t] = sgn_i8(w[t]);
        }
        return;
    }

    // ---- sign + pool for rows ih = 2oh, 2oh+1 of batch b ----
    const int bo = bid - 768;               // b*14 + oh
    const int b = bo / 14, oh = bo % 14;
    const float* xb = x + (size_t)(b * 256) * 784 + (2 * oh) * 28;

    // Phase A: coalesced fp32 reads -> packed sign u32s in LDS + pool out.
    for (int i = t; i < 1792; i += 256) {   // 256 c x 7 q
        const int c = i / 7, q = i - c * 7;
        const float bc = bias[c];
        const float4 v0 = *(const float4*)(xb + c * 784 + 4 * q);
        const float4 v1 = *(const float4*)(xb + c * 784 + 28 + 4 * q);
        uint_t s0 = sgn_b(v0.x + bc) | (sgn_b(v0.y + bc) << 8) |
                    (sgn_b(v0.z + bc) << 16) | (sgn_b(v0.w + bc) << 24);
        uint_t s1 = sgn_b(v1.x + bc) | (sgn_b(v1.y + bc) << 8) |
                    (sgn_b(v1.z + bc) << 16) | (sgn_b(v1.w + bc) << 24);
        lsign[c * 7 + q] = s0;              // addr = i  -> conflict-free
        lsign[1792 + c * 7 + q] = s1;
        float2 pr;
        pr.x = 0.25f * (v0.x + v0.y + v1.x + v1.y);
        pr.y = 0.25f * (v0.z + v0.w + v1.z + v1.w);
        *(float2*)(pool + (size_t)(b * 256 + c) * 196 + oh * 14 + 2 * q) = pr;
    }
    __syncthreads();

    // Phase B: 4x4 byte transpose; out u32 at pos 4t..4t+3 <- ic {t+64e}.
    for (int i = t; i < 896; i += 256) {    // 2 rows x 7 q x 64 t
        const int tt = i & 63;
        const int q = (i >> 6) % 7;
        const int row = i / 448;
        uint_t d[4];
#pragma unroll
        for (int e = 0; e < 4; ++e)
            d[e] = lsign[row * 1792 + (tt + 64 * e) * 7 + q];  // banks 7t+q
        char* orow = a1p + (size_t)((b * 30 + 2 * oh + row + 1) * 30) * 256;
#pragma unroll
        for (int j = 0; j < 4; ++j) {
            uint_t o = ((d[0] >> (8 * j)) & 0xffu)
                     | (((d[1] >> (8 * j)) & 0xffu) << 8)
                     | (((d[2] >> (8 * j)) & 0xffu) << 16)
                     | (((d[3] >> (8 * j)) & 0xffu) << 24);
            *(uint_t*)(orow + (4 * q + j + 1) * 256 + 4 * tt) = o;
        }
    }

    // halo columns iwp = 0, 29 for both rows; halo rows via oh==0 blocks
    {
        char* orow0 = a1p + (size_t)((b * 30 + 2 * oh + 1) * 30) * 256;
        char* orow1 = a1p + (size_t)((b * 30 + 2 * oh + 2) * 30) * 256;
        orow0[t] = 0; orow0[29 * 256 + t] = 0;
        orow1[t] = 0; orow1[29 * 256 + t] = 0;
    }
    if (oh == 0) {
        char* r0  = a1p + (size_t)(b * 900) * 256;
        char* r29 = a1p + (size_t)(b * 900 + 29 * 30) * 256;
        for (int idx = t; idx < 30 * 256; idx += 256) { r0[idx] = 0; r29[idx] = 0; }
    }
}

// ---------------------------------------------------------------------------
// Kernel 2: conv1 (3x3 s2) as i8 GEMM (unchanged from R9). M=12544 N=256
// K=2304, BK=128 (18 steps), 784 blocks, 8 waves, depth-2 counted vmcnt.
// ---------------------------------------------------------------------------
__global__ __launch_bounds__(512) void conv1_i8(
    const char* __restrict__ a1p,       // [64][30][30][256] i8 (perm'd c)
    const char* __restrict__ bw1,       // [256][2304] i8 (k = tap*256+p)
    const float* __restrict__ alpha1, const float* __restrict__ beta1,
    const float* __restrict__ p,
    const float* __restrict__ rsb,
    const float* __restrict__ prg, const float* __restrict__ prb,
    const float* __restrict__ prz,
    float* __restrict__ out2,
    char* __restrict__ a2)              // [m][256] i8
{
    __shared__ char lA[2][64 * 128];
    __shared__ char lB[2][64 * 128];

    const int bid = blockIdx.x;
    const int wgid = (bid & 7) * 98 + (bid >> 3);   // 784 = 8*98
    const int mtile = wgid >> 2;
    const int ntile = wgid & 3;

    const int tid = threadIdx.x;
    const int wave = tid >> 6;
    const int lane = tid & 63;
    const int col = lane & 15;
    const int krow = lane >> 4;
    const int wr = wave >> 2;
    const int wc = wave & 3;
    const int l8 = lane >> 3;
    const int s8 = lane & 7;
    const int swz = ((s8 ^ l8) << 4);

    int pbA;
    {
        const int grow = wave * 8 + l8;
        const int m = mtile * 64 + grow;
        const int b = m / 196, r = m % 196;
        const int oh = r / 14, ow = r % 14;
        pbA = ((b * 30 + 2 * oh) * 30 + 2 * ow) * 256 + swz;
    }
    const int pbB = (ntile * 64 + wave * 8 + l8) * K1 + swz;

    int rswz[2];
#pragma unroll
    for (int ks = 0; ks < 2; ++ks)
        rswz[ks] = ((ks * 4 + krow) ^ (col & 7)) << 4;

    i32x4 acc[2] = {};

    auto stage = [&](int step, int buf) {
        const int tap = step >> 1;
        const int kc0 = (step & 1) << 7;
        const int kh = tap / 3, kw = tap - kh * 3;
        const int aoff = (kh * 30 + kw) * 256 + kc0;
        gload16(a1p + pbA + aoff, &lA[buf][0] + wave * 1024);
        gload16(bw1 + pbB + step * 128, &lB[buf][0] + wave * 1024);
    };

    stage(0, 0);

    int cur = 0;
    for (int step = 0; step < 18; ++step) {
        if (step + 1 < 18) {
            stage(step + 1, cur ^ 1);
            asm volatile("s_waitcnt vmcnt(2)" ::: "memory");
        } else {
            asm volatile("s_waitcnt vmcnt(0)" ::: "memory");
        }
        __builtin_amdgcn_s_barrier();
        __builtin_amdgcn_sched_barrier(0);

#pragma unroll
        for (int ks = 0; ks < 2; ++ks) {
            i32x4 bf[2], af;
#pragma unroll
            for (int im = 0; im < 2; ++im) {
                const int row = wr * 32 + im * 16 + col;
                bf[im] = *(const i32x4*)(&lA[cur][0] + row * 128 + rswz[ks]);
            }
            {
                const int row = wc * 16 + col;
                af = *(const i32x4*)(&lB[cur][0] + row * 128 + rswz[ks]);
            }
#pragma unroll
            for (int im = 0; im < 2; ++im)
                acc[im] = __builtin_amdgcn_mfma_i32_16x16x64_i8(
                    af, bf[im], acc[im], 0, 0, 0);
        }
        __builtin_amdgcn_sched_barrier(0);
        __builtin_amdgcn_s_barrier();
        cur ^= 1;
    }

#pragma unroll
    for (int im = 0; im < 2; ++im) {
        const int m = mtile * 64 + wr * 32 + im * 16 + col;
        const int b = m / 196, r = m % 196;
        const int n0 = ntile * 64 + wc * 16 + krow * 4;
        char spack[4];
#pragma unroll
        for (int j = 0; j < 4; ++j) {
            const int n = n0 + j;
            const int idx = (b * 256 + n) * 196 + r;
            float v = alpha1[n] * (float)acc[im][j] + beta1[n] + p[idx];
            const float t = v - prg[n];
            const float o = (t > 0.f ? t : prb[n] * t) + prz[n];
            out2[idx] = o;
            spack[j] = sgn_i8(o + rsb[n]);
        }
        *(char4*)(a2 + m * 256 + n0) = *(char4*)spack;
    }
}

// ---------------------------------------------------------------------------
// Kernel 3: both 1x1 convs, single-shot i8 GEMM (unchanged from R9).
// ---------------------------------------------------------------------------
__global__ __launch_bounds__(512) void conv1x1_i8(
    const char* __restrict__ a2,
    const char* __restrict__ bw2,
    const float* __restrict__ alpha2, const float* __restrict__ beta2,
    const float* __restrict__ out2,
    const float* __restrict__ prg, const float* __restrict__ prb,
    const float* __restrict__ prz,
    float* __restrict__ out)
{
    __shared__ char lA[2][64 * 128];
    __shared__ char lB[2][64 * 128];

    const int bid = blockIdx.x;
    const int wgid = (bid & 7) * 196 + (bid >> 3);  // 1568 = 8*196
    const int mtile = wgid >> 3;
    const int ntile = wgid & 7;

    const int tid = threadIdx.x;
    const int wave = tid >> 6;
    const int lane = tid & 63;
    const int col = lane & 15;
    const int krow = lane >> 4;
    const int wr = wave >> 2;
    const int wc = wave & 3;
    const int l8 = lane >> 3;
    const int s8 = lane & 7;
    const int swz = ((s8 ^ l8) << 4);

    const int pbA = (mtile * 64 + wave * 8 + l8) * 256 + swz;
    const int pbB = (ntile * 64 + wave * 8 + l8) * 256 + swz;

#pragma unroll
    for (int h = 0; h < 2; ++h) {
        gload16(a2 + pbA + h * 128, &lA[h][0] + wave * 1024);
        gload16(bw2 + pbB + h * 128, &lB[h][0] + wave * 1024);
    }
    asm volatile("s_waitcnt vmcnt(0)" ::: "memory");
    __builtin_amdgcn_s_barrier();
    __builtin_amdgcn_sched_barrier(0);

    i32x4 acc[2] = {};
#pragma unroll
    for (int ks = 0; ks < 4; ++ks) {
        const int h = ks >> 1, k2 = ks & 1;
        const int ro = ((k2 * 4 + krow) ^ (col & 7)) << 4;
        i32x4 bf[2], af;
#pragma unroll
        for (int im = 0; im < 2; ++im) {
            const int row = wr * 32 + im * 16 + col;
            bf[im] = *(const i32x4*)(&lA[h][0] + row * 128 + ro);
        }
        {
            const int row = wc * 16 + col;
            af = *(const i32x4*)(&lB[h][0] + row * 128 + ro);
        }
#pragma unroll
        for (int im = 0; im < 2; ++im)
            acc[im] = __builtin_amdgcn_mfma_i32_16x16x64_i8(
                af, bf[im], acc[im], 0, 0, 0);
    }

#pragma unroll
    for (int im = 0; im < 2; ++im) {
        const int m = mtile * 64 + wr * 32 + im * 16 + col;
        const int b = m / 196, r = m % 196;
#pragma unroll
        for (int j = 0; j < 4; ++j) {
            const int n = ntile * 64 + wc * 16 + krow * 4 + j;
            const int oc = n & 255;
            float v = alpha2[n] * (float)acc[im][j] + beta2[n]
                    + out2[(b * 256 + oc) * 196 + r];
            const float t = v - prg[oc];
            out[(size_t)(b * 512 + n) * 196 + r] =
                (t > 0.f ? t : prb[oc] * t) + prz[oc];
        }
    }
}

// ---------------------------------------------------------------------------
extern "C" void kernel_launch(void* const* d_in, const int* in_sizes, int n_in,
                              void* d_out, int out_size, void* d_ws, size_t ws_size,
                              hipStream_t stream)
{
    (void)in_sizes; (void)n_in; (void)out_size; (void)ws_size;

    const float* x         = (const float*)d_in[0];
    const float* rsign_b   = (const float*)d_in[1];
    const float* w1        = (const float*)d_in[2];
    const float* bn1_g     = (const float*)d_in[3];
    const float* bn1_b     = (const float*)d_in[4];
    const float* bn1_m     = (const float*)d_in[5];
    const float* bn1_v     = (const float*)d_in[6];
    const float* w21       = (const float*)d_in[7];
    const float* bn21_g    = (const float*)d_in[8];
    const float* bn21_b    = (const float*)d_in[9];
    const float* bn21_m    = (const float*)d_in[10];
    const float* bn21_v    = (const float*)d_in[11];
    const float* w22       = (const float*)d_in[12];
    const float* bn22_g    = (const float*)d_in[13];
    const float* bn22_b    = (const float*)d_in[14];
    const float* bn22_m    = (const float*)d_in[15];
    const float* bn22_v    = (const float*)d_in[16];
    const float* pr_gamma  = (const float*)d_in[17];
    const float* pr_beta   = (const float*)d_in[18];
    const float* pr_zeta   = (const float*)d_in[19];

    char* ws = (char*)d_ws;
    size_t off = 0;
    char* a1p   = (char*)(ws + off);  off += (size_t)14745600;      // 14.7MB i8
    char* bw1   = (char*)(ws + off);  off += (size_t)589824;        // 0.6MB i8
    char* bw2   = (char*)(ws + off);  off += (size_t)131072;        // 0.13MB
    float* pool = (float*)(ws + off); off += (size_t)3211264 * 4;   // 12.8MB
    float* out2 = (float*)(ws + off); off += (size_t)3211264 * 4;   // 12.8MB
    char* a2    = (char*)(ws + off);  off += (size_t)3211264;       // 3.2MB i8
    float* alpha1 = (float*)(ws + off); off += 1024;
    float* beta1  = (float*)(ws + off); off += 1024;
    float* alpha2 = (float*)(ws + off); off += 2048;
    float* beta2  = (float*)(ws + off); off += 2048;

    prep_sign<<<1664, 256, 0, stream>>>(
        w1, bn1_g, bn1_b, bn1_m, bn1_v,
        w21, bn21_g, bn21_b, bn21_m, bn21_v,
        w22, bn22_g, bn22_b, bn22_m, bn22_v,
        x, rsign_b,
        bw1, bw2, alpha1, beta1, alpha2, beta2, a1p, pool);

    conv1_i8<<<784, 512, 0, stream>>>(
        a1p, bw1, alpha1, beta1, pool, rsign_b,
        pr_gamma, pr_beta, pr_zeta, out2, a2);

    conv1x1_i8<<<1568, 512, 0, stream>>>(
        a2, bw2, alpha2, beta2, out2,
        pr_gamma, pr_beta, pr_zeta, (float*)d_out);
}

// Round 12
// 60.919 us; speedup vs baseline: 2.3746x; 1.0132x over previous
//
#include <hip/hip_runtime.h>
#include <stdint.h>

#define EPS_BN 1e-5f

#define C 256
#define H 28
#define W 28
#define R196 196
#define M_TOT 12544
#define K1 2304

typedef __attribute__((ext_vector_type(4))) int   i32x4;
typedef __attribute__((ext_vector_type(4))) float f32x4;
typedef unsigned short ushort_t;
typedef unsigned int uint_t;

__device__ __forceinline__ char sgn_i8(float v) {
    return v > 0.f ? (char)1 : (v < 0.f ? (char)-1 : (char)0);
}
__device__ __forceinline__ uint_t sgn_b(float v) {
    return (uint_t)(unsigned char)sgn_i8(v);
}

__device__ __forceinline__ void gload16(const void* g, void* l) {
    __builtin_amdgcn_global_load_lds(
        (const __attribute__((address_space(1))) void*)g,
        (__attribute__((address_space(3))) void*)l, 16, 0, 0);
}

// channel-position permutation for conv1's K axis (a1p and bw1 share it):
//   p(ic) = ((ic & 63) << 2) | (ic >> 6);  ic(p) = ((p & 3) << 6) | (p >> 2)

// ---------------------------------------------------------------------------
// Kernel 1: blocks 0..767 weight prep; blocks 768..2559 sign(x+bias)->a1p
// (padded NHWC i8, permuted channels) + 2x2 avgpool (fp32).
// Sign part: 2 blocks per (b,oh), each handling channels {32hh+tl+64e}.
// ---------------------------------------------------------------------------
__global__ __launch_bounds__(256) void prep_sign(
    const float* __restrict__ w1,
    const float* __restrict__ bn1_g, const float* __restrict__ bn1_b,
    const float* __restrict__ bn1_m, const float* __restrict__ bn1_v,
    const float* __restrict__ w21,
    const float* __restrict__ bn21_g, const float* __restrict__ bn21_b,
    const float* __restrict__ bn21_m, const float* __restrict__ bn21_v,
    const float* __restrict__ w22,
    const float* __restrict__ bn22_g, const float* __restrict__ bn22_b,
    const float* __restrict__ bn22_m, const float* __restrict__ bn22_v,
    const float* __restrict__ x, const float* __restrict__ bias,
    char* __restrict__ bw1, char* __restrict__ bw2,
    float* __restrict__ alpha1, float* __restrict__ beta1,
    float* __restrict__ alpha2, float* __restrict__ beta2,
    char* __restrict__ a1p, float* __restrict__ pool)
{
    __shared__ uint_t lsign[1792];            // [row][lc][q], 7KB
    float* red = (float*)lsign;
    const int bid = blockIdx.x;
    const int t = threadIdx.x;

    if (bid < 768) {
        if (bid < 256) {
            const int oc = bid;
            const float* w = w1 + oc * K1;
            float s = 0.f;
            for (int i = t; i < K1; i += 256) s += fabsf(w[i]);
            red[t] = s; __syncthreads();
            for (int o = 128; o > 0; o >>= 1) {
                if (t < o) red[t] += red[t + o];
                __syncthreads();
            }
            const float scale = red[0] * (1.f / (float)K1);
            if (t == 0) {
                const float inv = bn1_g[oc] * rsqrtf(bn1_v[oc] + EPS_BN);
                alpha1[oc] = scale * inv;
                beta1[oc]  = bn1_b[oc] - bn1_m[oc] * inv;
            }
            // K index = tap*256 + p ; ic(p) with p = t
            const int ic = ((t & 3) << 6) | (t >> 2);
#pragma unroll
            for (int tap = 0; tap < 9; ++tap)
                bw1[oc * K1 + tap * 256 + t] = sgn_i8(w[ic * 9 + tap]);
        } else {
            const bool br2 = (bid >= 512);
            const int oc = (bid - 256) & 255;
            const float* w = (br2 ? w22 : w21) + oc * 256;
            red[t] = fabsf(w[t]); __syncthreads();
            for (int o = 128; o > 0; o >>= 1) {
                if (t < o) red[t] += red[t + o];
                __syncthreads();
            }
            const float scale = red[0] * (1.f / 256.f);
            const int n = oc + (br2 ? 256 : 0);
            if (t == 0) {
                const float g = br2 ? bn22_g[oc] : bn21_g[oc];
                const float b = br2 ? bn22_b[oc] : bn21_b[oc];
                const float m = br2 ? bn22_m[oc] : bn21_m[oc];
                const float v = br2 ? bn22_v[oc] : bn21_v[oc];
                const float inv = g * rsqrtf(v + EPS_BN);
                alpha2[n] = scale * inv;
                beta2[n]  = b - m * inv;
            }
            bw2[n * 256 + t] = sgn_i8(w[t]);
        }
        return;
    }

    // ---- sign + pool, half-channel block ----
    const int sb = bid - 768;               // (b*14 + oh)*2 + hh
    const int hh = sb & 1;
    const int bo = sb >> 1;
    const int b = bo / 14, oh = bo % 14;
    const float* xb = x + (size_t)(b * 256) * 784 + (2 * oh) * 28;

    // Phase A: coalesced fp32 reads -> packed sign u32s in LDS + fp32 pool.
    for (int i = t; i < 896; i += 256) {    // 128 lc x 7 q
        const int lc = i / 7, q = i - lc * 7;
        const int c = 64 * (lc >> 5) + 32 * hh + (lc & 31);
        const float bc = bias[c];
        const float4 v0 = *(const float4*)(xb + c * 784 + 4 * q);
        const float4 v1 = *(const float4*)(xb + c * 784 + 28 + 4 * q);
        uint_t s0 = sgn_b(v0.x + bc) | (sgn_b(v0.y + bc) << 8) |
                    (sgn_b(v0.z + bc) << 16) | (sgn_b(v0.w + bc) << 24);
        uint_t s1 = sgn_b(v1.x + bc) | (sgn_b(v1.y + bc) << 8) |
                    (sgn_b(v1.z + bc) << 16) | (sgn_b(v1.w + bc) << 24);
        lsign[lc * 7 + q] = s0;
        lsign[896 + lc * 7 + q] = s1;
        float2 pr;
        pr.x = 0.25f * (v0.x + v0.y + v1.x + v1.y);
        pr.y = 0.25f * (v0.z + v0.w + v1.z + v1.w);
        *(float2*)(pool + (size_t)(b * 256 + c) * 196 + oh * 14 + 2 * q) = pr;
    }
    __syncthreads();

    // Phase B: 4x4 byte transpose; word tt covers channels {32hh+tl+64e}.
    for (int i = t; i < 448; i += 256) {    // 2 rows x 7 q x 32 tl
        const int tl = i & 31;
        const int q = (i >> 5) % 7;
        const int row = i / 224;
        const int tt = 32 * hh + tl;
        uint_t d[4];
#pragma unroll
        for (int e = 0; e < 4; ++e)
            d[e] = lsign[row * 896 + (tl + 32 * e) * 7 + q];
        char* orow = a1p + (size_t)((b * 30 + 2 * oh + row + 1) * 30) * 256;
#pragma unroll
        for (int j = 0; j < 4; ++j) {
            uint_t o = ((d[0] >> (8 * j)) & 0xffu)
                     | (((d[1] >> (8 * j)) & 0xffu) << 8)
                     | (((d[2] >> (8 * j)) & 0xffu) << 16)
                     | (((d[3] >> (8 * j)) & 0xffu) << 24);
            *(uint_t*)(orow + (4 * q + j + 1) * 256 + 4 * tt) = o;
        }
    }

    // halo columns iwp = 0, 29: this block zeroes its 128-byte channel half
    {
        char* orow0 = a1p + (size_t)((b * 30 + 2 * oh + 1) * 30) * 256;
        char* orow1 = a1p + (size_t)((b * 30 + 2 * oh + 2) * 30) * 256;
        const int bo2 = 128 * hh + (t & 127);
        if (t < 128) { orow0[bo2] = 0; orow1[bo2] = 0; }
        else         { orow0[29 * 256 + bo2] = 0; orow1[29 * 256 + bo2] = 0; }
    }
    if (oh == 0) {
        char* r0  = a1p + (size_t)(b * 900) * 256;
        char* r29 = a1p + (size_t)(b * 900 + 29 * 30) * 256;
        for (int idx = t; idx < 30 * 128; idx += 256) {
            const int colo = (idx >> 7) * 256 + 128 * hh + (idx & 127);
            r0[colo] = 0; r29[colo] = 0;
        }
    }
}

// ---------------------------------------------------------------------------
// Kernel 2: conv1 (3x3 s2) i8 GEMM (structure = R9/R10, fp32 pool/out2).
// ---------------------------------------------------------------------------
__global__ __launch_bounds__(512) void conv1_i8(
    const char* __restrict__ a1p,       // [64][30][30][256] i8 (perm'd c)
    const char* __restrict__ bw1,       // [256][2304] i8 (k = tap*256+p)
    const float* __restrict__ alpha1, const float* __restrict__ beta1,
    const float* __restrict__ p,
    const float* __restrict__ rsb,
    const float* __restrict__ prg, const float* __restrict__ prb,
    const float* __restrict__ prz,
    float* __restrict__ out2,
    char* __restrict__ a2)              // [m][256] i8
{
    __shared__ char lA[2][64 * 128];
    __shared__ char lB[2][64 * 128];

    const int bid = blockIdx.x;
    const int wgid = (bid & 7) * 98 + (bid >> 3);   // 784 = 8*98
    const int mtile = wgid >> 2;
    const int ntile = wgid & 3;

    const int tid = threadIdx.x;
    const int wave = tid >> 6;
    const int lane = tid & 63;
    const int col = lane & 15;
    const int krow = lane >> 4;
    const int wr = wave >> 2;
    const int wc = wave & 3;
    const int l8 = lane >> 3;
    const int s8 = lane & 7;
    const int swz = ((s8 ^ l8) << 4);

    int pbA;
    {
        const int grow = wave * 8 + l8;
        const int m = mtile * 64 + grow;
        const int b = m / 196, r = m % 196;
        const int oh = r / 14, ow = r % 14;
        pbA = ((b * 30 + 2 * oh) * 30 + 2 * ow) * 256 + swz;
    }
    const int pbB = (ntile * 64 + wave * 8 + l8) * K1 + swz;

    int rswz[2];
#pragma unroll
    for (int ks = 0; ks < 2; ++ks)
        rswz[ks] = ((ks * 4 + krow) ^ (col & 7)) << 4;

    i32x4 acc[2] = {};

    auto stage = [&](int step, int buf) {
        const int tap = step >> 1;
        const int kc0 = (step & 1) << 7;
        const int kh = tap / 3, kw = tap - kh * 3;
        const int aoff = (kh * 30 + kw) * 256 + kc0;
        gload16(a1p + pbA + aoff, &lA[buf][0] + wave * 1024);
        gload16(bw1 + pbB + step * 128, &lB[buf][0] + wave * 1024);
    };

    stage(0, 0);

    int cur = 0;
    for (int step = 0; step < 18; ++step) {
        if (step + 1 < 18) {
            stage(step + 1, cur ^ 1);
            asm volatile("s_waitcnt vmcnt(2)" ::: "memory");
        } else {
            asm volatile("s_waitcnt vmcnt(0)" ::: "memory");
        }
        __builtin_amdgcn_s_barrier();
        __builtin_amdgcn_sched_barrier(0);

#pragma unroll
        for (int ks = 0; ks < 2; ++ks) {
            i32x4 bf[2], af;
#pragma unroll
            for (int im = 0; im < 2; ++im) {
                const int row = wr * 32 + im * 16 + col;
                bf[im] = *(const i32x4*)(&lA[cur][0] + row * 128 + rswz[ks]);
            }
            {
                const int row = wc * 16 + col;
                af = *(const i32x4*)(&lB[cur][0] + row * 128 + rswz[ks]);
            }
#pragma unroll
            for (int im = 0; im < 2; ++im)
                acc[im] = __builtin_amdgcn_mfma_i32_16x16x64_i8(
                    af, bf[im], acc[im], 0, 0, 0);
        }
        __builtin_amdgcn_sched_barrier(0);
        __builtin_amdgcn_s_barrier();
        cur ^= 1;
    }

#pragma unroll
    for (int im = 0; im < 2; ++im) {
        const int m = mtile * 64 + wr * 32 + im * 16 + col;
        const int b = m / 196, r = m % 196;
        const int n0 = ntile * 64 + wc * 16 + krow * 4;
        char spack[4];
#pragma unroll
        for (int j = 0; j < 4; ++j) {
            const int n = n0 + j;
            const int idx = (b * 256 + n) * 196 + r;
            float v = alpha1[n] * (float)acc[im][j] + beta1[n] + p[idx];
            const float t = v - prg[n];
            const float o = (t > 0.f ? t : prb[n] * t) + prz[n];
            out2[idx] = o;
            spack[j] = sgn_i8(o + rsb[n]);
        }
        *(char4*)(a2 + m * 256 + n0) = *(char4*)spack;
    }
}

// ---------------------------------------------------------------------------
// Kernel 3: both 1x1 convs, single-shot i8 GEMM (fp32 out2 residual).
// ---------------------------------------------------------------------------
__global__ __launch_bounds__(512) void conv1x1_i8(
    const char* __restrict__ a2,
    const char* __restrict__ bw2,
    const float* __restrict__ alpha2, const float* __restrict__ beta2,
    const float* __restrict__ out2,
    const float* __restrict__ prg, const float* __restrict__ prb,
    const float* __restrict__ prz,
    float* __restrict__ out)
{
    __shared__ char lA[2][64 * 128];
    __shared__ char lB[2][64 * 128];

    const int bid = blockIdx.x;
    const int wgid = (bid & 7) * 196 + (bid >> 3);  // 1568 = 8*196
    const int mtile = wgid >> 3;
    const int ntile = wgid & 7;

    const int tid = threadIdx.x;
    const int wave = tid >> 6;
    const int lane = tid & 63;
    const int col = lane & 15;
    const int krow = lane >> 4;
    const int wr = wave >> 2;
    const int wc = wave & 3;
    const int l8 = lane >> 3;
    const int s8 = lane & 7;
    const int swz = ((s8 ^ l8) << 4);

    const int pbA = (mtile * 64 + wave * 8 + l8) * 256 + swz;
    const int pbB = (ntile * 64 + wave * 8 + l8) * 256 + swz;

#pragma unroll
    for (int h = 0; h < 2; ++h) {
        gload16(a2 + pbA + h * 128, &lA[h][0] + wave * 1024);
        gload16(bw2 + pbB + h * 128, &lB[h][0] + wave * 1024);
    }
    asm volatile("s_waitcnt vmcnt(0)" ::: "memory");
    __builtin_amdgcn_s_barrier();
    __builtin_amdgcn_sched_barrier(0);

    i32x4 acc[2] = {};
#pragma unroll
    for (int ks = 0; ks < 4; ++ks) {
        const int h = ks >> 1, k2 = ks & 1;
        const int ro = ((k2 * 4 + krow) ^ (col & 7)) << 4;
        i32x4 bf[2], af;
#pragma unroll
        for (int im = 0; im < 2; ++im) {
            const int row = wr * 32 + im * 16 + col;
            bf[im] = *(const i32x4*)(&lA[h][0] + row * 128 + ro);
        }
        {
            const int row = wc * 16 + col;
            af = *(const i32x4*)(&lB[h][0] + row * 128 + ro);
        }
#pragma unroll
        for (int im = 0; im < 2; ++im)
            acc[im] = __builtin_amdgcn_mfma_i32_16x16x64_i8(
                af, bf[im], acc[im], 0, 0, 0);
    }

#pragma unroll
    for (int im = 0; im < 2; ++im) {
        const int m = mtile * 64 + wr * 32 + im * 16 + col;
        const int b = m / 196, r = m % 196;
#pragma unroll
        for (int j = 0; j < 4; ++j) {
            const int n = ntile * 64 + wc * 16 + krow * 4 + j;
            const int oc = n & 255;
            float v = alpha2[n] * (float)acc[im][j] + beta2[n]
                    + out2[(b * 256 + oc) * 196 + r];
            const float t = v - prg[oc];
            out[(size_t)(b * 512 + n) * 196 + r] =
                (t > 0.f ? t : prb[oc] * t) + prz[oc];
        }
    }
}

// ---------------------------------------------------------------------------
extern "C" void kernel_launch(void* const* d_in, const int* in_sizes, int n_in,
                              void* d_out, int out_size, void* d_ws, size_t ws_size,
                              hipStream_t stream)
{
    (void)in_sizes; (void)n_in; (void)out_size; (void)ws_size;

    const float* x         = (const float*)d_in[0];
    const float* rsign_b   = (const float*)d_in[1];
    const float* w1        = (const float*)d_in[2];
    const float* bn1_g     = (const float*)d_in[3];
    const float* bn1_b     = (const float*)d_in[4];
    const float* bn1_m     = (const float*)d_in[5];
    const float* bn1_v     = (const float*)d_in[6];
    const float* w21       = (const float*)d_in[7];
    const float* bn21_g    = (const float*)d_in[8];
    const float* bn21_b    = (const float*)d_in[9];
    const float* bn21_m    = (const float*)d_in[10];
    const float* bn21_v    = (const float*)d_in[11];
    const float* w22       = (const float*)d_in[12];
    const float* bn22_g    = (const float*)d_in[13];
    const float* bn22_b    = (const float*)d_in[14];
    const float* bn22_m    = (const float*)d_in[15];
    const float* bn22_v    = (const float*)d_in[16];
    const float* pr_gamma  = (const float*)d_in[17];
    const float* pr_beta   = (const float*)d_in[18];
    const float* pr_zeta   = (const float*)d_in[19];

    char* ws = (char*)d_ws;
    size_t off = 0;
    char* a1p     = (char*)(ws + off);  off += (size_t)14745600;      // i8
    char* bw1     = (char*)(ws + off);  off += (size_t)589824;        // i8
    char* bw2     = (char*)(ws + off);  off += (size_t)131072;        // i8
    float* pool   = (float*)(ws + off); off += (size_t)3211264 * 4;   // fp32
    float* out2   = (float*)(ws + off); off += (size_t)3211264 * 4;   // fp32
    char* a2      = (char*)(ws + off);  off += (size_t)3211264;       // i8
    float* alpha1 = (float*)(ws + off); off += 1024;
    float* beta1  = (float*)(ws + off); off += 1024;
    float* alpha2 = (float*)(ws + off); off += 2048;
    float* beta2  = (float*)(ws + off); off += 2048;

    prep_sign<<<2560, 256, 0, stream>>>(
        w1, bn1_g, bn1_b, bn1_m, bn1_v,
        w21, bn21_g, bn21_b, bn21_m, bn21_v,
        w22, bn22_g, bn22_b, bn22_m, bn22_v,
        x, rsign_b,
        bw1, bw2, alpha1, beta1, alpha2, beta2, a1p, pool);

    conv1_i8<<<784, 512, 0, stream>>>(
        a1p, bw1, alpha1, beta1, pool, rsign_b,
        pr_gamma, pr_beta, pr_zeta, out2, a2);

    conv1x1_i8<<<1568, 512, 0, stream>>>(
        a2, bw2, alpha2, beta2, out2,
        pr_gamma, pr_beta, pr_zeta, (float*)d_out);
}